// Round 17
// baseline (730.087 us; speedup 1.0000x reference)
//
#include <hip/hip_runtime.h>
#include <hip/hip_fp16.h>
#include <math.h>

// ---------------------------------------------------------------------------
// Pipeline:
//  k_zero2     : zero degree counters
//  k_deg       : in-degree count per dst (both graphs), int atomics
//  k_scan2     : 2 blocks (one per graph): exclusive scan -> roff, dinv,
//                + fused per-bucket cursor init (bcur = roff[bucket_lo])
//  k_part      : grid.y=graph; stage 4096 edges in LDS, histogram over 512
//                dst-buckets, reserve ranges, write u32 (dstLocal<<16|src)
//                grouped by bucket (requires N<65536, npb<65536 -- N=50000)
//  k_scatter3  : grid.y=graph; one block per bucket, LDS CSR cursors,
//                stream packed pairs -> csr[pos]=src (L2-window writes)
//  k_cnn       : conv1d(16,k40,s88)+relu + linear 80->40+relu -> seq/feats
//  k_gru       : tiled f32 GRU (best measured): 128 nodes/block, 512 thr,
//                weights+h+x in LDS, x-prefetch into regs
//  k_hw        : hs_g[n][0..39] = fp16(dinv*(feats@Wg)), row stride 64
//                (128B-aligned rows -> every k_agg2 gather = one cache line)
//  k_agg2      : BOTH graphs in one kernel: per node-wave, walk csr1 and
//                csr2 (8-deep gather ILP each), fused bias+relu+MLP -> out
// ---------------------------------------------------------------------------

#define NB      512   // dst buckets
#define MAXNPB  104   // max dst nodes per bucket (N=50000 -> npb=98)
#define PART_T  4096  // edges staged per k_part block
#define HSW     64    // hs row stride in halves (128B-aligned rows)

__global__ __launch_bounds__(512) void k_cnn(
    const float* __restrict__ x,       // [R][395]
    const float* __restrict__ conv_w,  // [16][40]
    const float* __restrict__ conv_b,  // [16]
    const float* __restrict__ lin_w,   // [40][80]
    const float* __restrict__ lin_b,   // [40]
    float* __restrict__ seq,           // [4][N][41]
    float* __restrict__ feats,         // [N][104]
    int nrows, int nnodes)
{
    __shared__ __align__(16) float smem[64 * 200];   // 51.2 KB (sig, then c)
    __shared__ __align__(16) float s_cw[16][44];
    __shared__ __align__(16) float s_lw[40][84];
    __shared__ float s_cb[16];
    __shared__ float s_lb[40];

    const int tid = threadIdx.x;
    const int r0  = blockIdx.x * 64;

    float sg[25];
    #pragma unroll
    for (int it = 0; it < 25; ++it) {
        int i = tid + it * 512;
        int row = i / 200, e = i - row * 200;
        int p = e / 40, kk = e - p * 40;
        int gr = r0 + row; if (gr >= nrows) gr = nrows - 1;
        sg[it] = x[(size_t)gr * 395 + 3 + 88 * p + kk];
    }

    for (int i = tid; i < 640;  i += 512) s_cw[i / 40][i % 40] = conv_w[i];
    for (int i = tid; i < 3200; i += 512) s_lw[i / 80][i % 80] = lin_w[i];
    if (tid < 16) s_cb[tid] = conv_b[tid];
    if (tid >= 64 && tid < 104) s_lb[tid - 64] = lin_b[tid - 64];

    if (tid < 64) {
        int gr = r0 + tid;
        if (gr < nrows) {
            float y = x[(size_t)gr * 395 + 2];
            int node = gr / 5, t = gr - node * 5;
            if (t < 4) seq[(t * nnodes + node) * 41 + 40] = y;
        }
    }

    #pragma unroll
    for (int it = 0; it < 25; ++it) {
        int i = tid + it * 512;
        int row = i / 200, e = i - row * 200;
        smem[row * 200 + e] = sg[it];
    }
    __syncthreads();

    const int row = tid >> 3, cg = tid & 7;
    float creg[2][5];
    {
        float acc[2][5];
        #pragma unroll
        for (int cc = 0; cc < 2; ++cc) {
            float b = s_cb[2 * cg + cc];
            #pragma unroll
            for (int p = 0; p < 5; ++p) acc[cc][p] = b;
        }
        #pragma unroll
        for (int k4 = 0; k4 < 40; k4 += 4) {
            float4 sv[5];
            #pragma unroll
            for (int p = 0; p < 5; ++p)
                sv[p] = *(const float4*)&smem[row * 200 + p * 40 + k4];
            #pragma unroll
            for (int cc = 0; cc < 2; ++cc) {
                float4 w4 = *(const float4*)&s_cw[2 * cg + cc][k4];
                #pragma unroll
                for (int p = 0; p < 5; ++p)
                    acc[cc][p] += w4.x * sv[p].x + w4.y * sv[p].y + w4.z * sv[p].z + w4.w * sv[p].w;
            }
        }
        #pragma unroll
        for (int cc = 0; cc < 2; ++cc)
            #pragma unroll
            for (int p = 0; p < 5; ++p) creg[cc][p] = fmaxf(acc[cc][p], 0.0f);
    }
    __syncthreads();

    #pragma unroll
    for (int cc = 0; cc < 2; ++cc)
        #pragma unroll
        for (int p = 0; p < 5; ++p)
            smem[row * 84 + (2 * cg + cc) * 5 + p] = creg[cc][p];
    __syncthreads();

    {
        const int jg = tid & 7;
        float acc[5];
        #pragma unroll
        for (int jj = 0; jj < 5; ++jj) acc[jj] = s_lb[5 * jg + jj];
        #pragma unroll
        for (int i4 = 0; i4 < 80; i4 += 4) {
            float4 c0 = *(const float4*)&smem[row * 84 + i4];
            #pragma unroll
            for (int jj = 0; jj < 5; ++jj) {
                float4 w4 = *(const float4*)&s_lw[5 * jg + jj][i4];
                acc[jj] += w4.x * c0.x + w4.y * c0.y + w4.z * c0.z + w4.w * c0.w;
            }
        }
        int gr = r0 + row;
        if (gr < nrows) {
            int node = gr / 5, t = gr - node * 5;
            #pragma unroll
            for (int jj = 0; jj < 5; ++jj) {
                float v = fmaxf(acc[jj], 0.0f);
                if (t < 4) seq[(t * nnodes + node) * 41 + 5 * jg + jj] = v;
                else       feats[node * 104 + 5 * jg + jj] = v;
            }
        }
    }
}

// tiled f32 GRU (best measured): 128 nodes/block, 512 threads,
// weights+h+x in LDS, next-step x prefetched into registers.
__global__ __launch_bounds__(512) void k_gru(
    const float* __restrict__ seq,    // [4][N][41]
    const float* __restrict__ w_ih,   // [192][41]
    const float* __restrict__ w_hh,   // [192][64]
    const float* __restrict__ b_ih,
    const float* __restrict__ b_hh,
    float* __restrict__ feats,        // [N][104]
    int nnodes)
{
    __shared__ __align__(16) float s_wi[41][192];
    __shared__ __align__(16) float s_wh[64][192];
    __shared__ __align__(16) float s_h[64][132];
    __shared__ __align__(16) float s_x[41][132];
    __shared__ float s_bi[192], s_bh[192];

    const int tid  = threadIdx.x;
    const int nblk = blockIdx.x * 128;

    float xr[11];
    #pragma unroll
    for (int r = 0; r < 11; ++r) {
        int i = tid + r * 512;
        if (i < 5248) {
            int nl = i / 41, k = i - nl * 41;
            int node = nblk + nl; if (node >= nnodes) node = nnodes - 1;
            xr[r] = seq[(size_t)node * 41 + k];
        }
    }

    for (int i = tid; i < 192 * 41; i += 512) { int g = i / 41, k = i - g * 41; s_wi[k][g] = w_ih[i]; }
    for (int i = tid; i < 192 * 64; i += 512) { int g = i >> 6,  k = i & 63;    s_wh[k][g] = w_hh[i]; }
    if (tid < 192) { s_bi[tid] = b_ih[tid]; s_bh[tid] = b_hh[tid]; }
    for (int i = tid; i < 64 * 132; i += 512) ((float*)s_h)[i] = 0.0f;

    #pragma unroll
    for (int r = 0; r < 11; ++r) {
        int i = tid + r * 512;
        if (i < 5248) { int nl = i / 41, k = i - nl * 41; s_x[k][nl] = xr[r]; }
    }
    __syncthreads();

    const int jg = tid & 31, ngp = tid >> 5;
    const int j0 = 2 * jg, n0 = 8 * ngp;

    float hreg[2][8];
    #pragma unroll
    for (int a = 0; a < 2; ++a)
        #pragma unroll
        for (int b = 0; b < 8; ++b) hreg[a][b] = 0.0f;

    for (int t = 0; t < 4; ++t) {
        if (t < 3) {
            #pragma unroll
            for (int r = 0; r < 11; ++r) {
                int i = tid + r * 512;
                if (i < 5248) {
                    int nl = i / 41, k = i - nl * 41;
                    int node = nblk + nl; if (node >= nnodes) node = nnodes - 1;
                    xr[r] = seq[(size_t)((t + 1) * nnodes + node) * 41 + k];
                }
            }
        }

        float ar[2][8], az[2][8], ani[2][8], anh[2][8];
        #pragma unroll
        for (int a = 0; a < 2; ++a)
            #pragma unroll
            for (int b = 0; b < 8; ++b) { ar[a][b]=0.f; az[a][b]=0.f; ani[a][b]=0.f; anh[a][b]=0.f; }

        for (int k = 0; k < 41; ++k) {
            float4 xa = *(const float4*)&s_x[k][n0];
            float4 xb = *(const float4*)&s_x[k][n0 + 4];
            float xv[8] = {xa.x,xa.y,xa.z,xa.w,xb.x,xb.y,xb.z,xb.w};
            float2 wr = *(const float2*)&s_wi[k][j0];
            float2 wz = *(const float2*)&s_wi[k][64 + j0];
            float2 wn = *(const float2*)&s_wi[k][128 + j0];
            #pragma unroll
            for (int nn = 0; nn < 8; ++nn) {
                ar[0][nn] += wr.x*xv[nn]; ar[1][nn] += wr.y*xv[nn];
                az[0][nn] += wz.x*xv[nn]; az[1][nn] += wz.y*xv[nn];
                ani[0][nn]+= wn.x*xv[nn]; ani[1][nn]+= wn.y*xv[nn];
            }
        }
        for (int k = 0; k < 64; ++k) {
            float4 ha = *(const float4*)&s_h[k][n0];
            float4 hb = *(const float4*)&s_h[k][n0 + 4];
            float hv[8] = {ha.x,ha.y,ha.z,ha.w,hb.x,hb.y,hb.z,hb.w};
            float2 wr = *(const float2*)&s_wh[k][j0];
            float2 wz = *(const float2*)&s_wh[k][64 + j0];
            float2 wn = *(const float2*)&s_wh[k][128 + j0];
            #pragma unroll
            for (int nn = 0; nn < 8; ++nn) {
                ar[0][nn] += wr.x*hv[nn]; ar[1][nn] += wr.y*hv[nn];
                az[0][nn] += wz.x*hv[nn]; az[1][nn] += wz.y*hv[nn];
                anh[0][nn]+= wn.x*hv[nn]; anh[1][nn]+= wn.y*hv[nn];
            }
        }

        #pragma unroll
        for (int jj = 0; jj < 2; ++jj) {
            int j = j0 + jj;
            float br  = s_bi[j]      + s_bh[j];
            float bz  = s_bi[64 + j] + s_bh[64 + j];
            float bin = s_bi[128 + j], bhn = s_bh[128 + j];
            #pragma unroll
            for (int nn = 0; nn < 8; ++nn) {
                float r = 1.0f / (1.0f + expf(-(ar[jj][nn] + br)));
                float z = 1.0f / (1.0f + expf(-(az[jj][nn] + bz)));
                float g = tanhf(ani[jj][nn] + bin + r * (anh[jj][nn] + bhn));
                hreg[jj][nn] = (1.0f - z) * g + z * hreg[jj][nn];
            }
        }
        __syncthreads();

        if (t < 3) {
            #pragma unroll
            for (int jj = 0; jj < 2; ++jj) {
                *(float4*)&s_h[j0+jj][n0]     = make_float4(hreg[jj][0],hreg[jj][1],hreg[jj][2],hreg[jj][3]);
                *(float4*)&s_h[j0+jj][n0 + 4] = make_float4(hreg[jj][4],hreg[jj][5],hreg[jj][6],hreg[jj][7]);
            }
            #pragma unroll
            for (int r = 0; r < 11; ++r) {
                int i = tid + r * 512;
                if (i < 5248) { int nl = i / 41, k = i - nl * 41; s_x[k][nl] = xr[r]; }
            }
            __syncthreads();
        }
    }

    #pragma unroll
    for (int jj = 0; jj < 2; ++jj)
        #pragma unroll
        for (int nn = 0; nn < 8; ++nn) {
            int node = nblk + n0 + nn;
            if (node < nnodes) feats[node * 104 + 40 + j0 + jj] = hreg[jj][nn];
        }
}

__global__ __launch_bounds__(256) void k_hw(
    const float* __restrict__ feats,   // [N][104]
    const float* __restrict__ w1,      // [104][40]
    const float* __restrict__ w2,      // [104][40]
    const float* __restrict__ dinv1,
    const float* __restrict__ dinv2,
    __half* __restrict__ hs1,          // [N][HSW] fp16, 40 used
    __half* __restrict__ hs2,
    int nnodes)
{
    __shared__ __align__(16) float s_f[128][108];
    __shared__ __align__(16) float s_w[80][108];
    __shared__ float s_d[2][128];

    const int tid  = threadIdx.x;
    const int nblk = blockIdx.x * 128;

    for (int i = tid; i < 128 * 104; i += 256) {
        int n = i / 104, k = i - n * 104;
        int node = nblk + n; if (node >= nnodes) node = nnodes - 1;
        s_f[n][k] = feats[node * 104 + k];
    }
    for (int i = tid; i < 80 * 104; i += 256) {
        int o = i / 104, k = i - o * 104;
        s_w[o][k] = (o < 40) ? w1[k * 40 + o] : w2[k * 40 + (o - 40)];
    }
    if (tid < 128) {
        int node = nblk + tid; if (node >= nnodes) node = nnodes - 1;
        s_d[0][tid] = dinv1[node]; s_d[1][tid] = dinv2[node];
    }
    __syncthreads();

    const int og = tid & 7, ngp = tid >> 3;
    const int o0 = 10 * og, n0 = 4 * ngp;
    float acc[4][10];
    #pragma unroll
    for (int a = 0; a < 4; ++a)
        #pragma unroll
        for (int b = 0; b < 10; ++b) acc[a][b] = 0.0f;

    for (int k4 = 0; k4 < 104; k4 += 4) {
        float4 f[4];
        #pragma unroll
        for (int nn = 0; nn < 4; ++nn) f[nn] = *(const float4*)&s_f[n0 + nn][k4];
        #pragma unroll
        for (int oo = 0; oo < 10; ++oo) {
            float4 w4 = *(const float4*)&s_w[o0 + oo][k4];
            #pragma unroll
            for (int nn = 0; nn < 4; ++nn)
                acc[nn][oo] += w4.x * f[nn].x + w4.y * f[nn].y + w4.z * f[nn].z + w4.w * f[nn].w;
        }
    }
    #pragma unroll
    for (int nn = 0; nn < 4; ++nn) {
        int node = nblk + n0 + nn;
        if (node >= nnodes) continue;
        #pragma unroll
        for (int oo = 0; oo < 10; oo += 2) {
            int o = o0 + oo;
            float dscale = (o < 40) ? s_d[0][n0 + nn] : s_d[1][n0 + nn];
            __half2 h2 = __floats2half2_rn(dscale * acc[nn][oo], dscale * acc[nn][oo + 1]);
            if (o < 40) *(__half2*)&hs1[node * HSW + o]        = h2;
            else        *(__half2*)&hs2[node * HSW + (o - 40)] = h2;
        }
    }
}

__global__ void k_zero2(int* a, int* b, int n) {
    int i = blockIdx.x * 256 + threadIdx.x;
    if (i < n) { a[i] = 0; b[i] = 0; }
}

__global__ void k_deg(const int* __restrict__ d1, const int* __restrict__ d2,
                      int* c1, int* c2, int E) {
    int i = blockIdx.x * 256 + threadIdx.x;
    if (i < E) { atomicAdd(&c1[d1[i]], 1); atomicAdd(&c2[d2[i]], 1); }
}

// 2 blocks: blockIdx.x==0 -> graph1, ==1 -> graph2. Scan + dinv + fused bcur.
__global__ __launch_bounds__(1024) void k_scan2(
    const int* __restrict__ cnt1, int* __restrict__ roff1, float* __restrict__ dinv1,
    const int* __restrict__ cnt2, int* __restrict__ roff2, float* __restrict__ dinv2,
    int* __restrict__ bcur, int npb, int n)
{
    const int* cnt  = blockIdx.x ? cnt2  : cnt1;
    int*       roff = blockIdx.x ? roff2 : roff1;
    float*     dinv = blockIdx.x ? dinv2 : dinv1;
    int*       bc   = bcur + (blockIdx.x ? NB : 0);

    __shared__ int sp[1024];
    int t = threadIdx.x;
    int C = (n + 1023) >> 10;
    int i0 = t * C, i1 = min(i0 + C, n);
    int s = 0;
    for (int i = i0; i < i1; ++i) s += cnt[i];
    sp[t] = s;
    __syncthreads();
    for (int off = 1; off < 1024; off <<= 1) {
        int v = (t >= off) ? sp[t - off] : 0;
        __syncthreads();
        sp[t] += v;
        __syncthreads();
    }
    int run = sp[t] - s;
    for (int i = i0; i < i1; ++i) {
        int c = cnt[i];
        roff[i] = run;
        dinv[i] = rsqrtf((float)(c + 1));
        run += c;
    }
    if (t == 1023) roff[n] = sp[1023];
    __syncthreads();
    if (t < NB) {
        int lo = min(t * npb, n);
        bc[t] = roff[lo];
    }
}

// grid.y selects graph. Stage PART_T edges in LDS, histogram over NB buckets,
// reserve exact global ranges, write u32 (dstLocal<<16 | src) by bucket.
// Requires src < 65536*? src < 65536 and dstLocal < 65536 (N=50000, npb=98).
__global__ __launch_bounds__(256) void k_part(
    const int* __restrict__ e1, const int* __restrict__ e2,
    int* __restrict__ bcur,             // [2*NB]
    unsigned int* __restrict__ pairs1,
    unsigned int* __restrict__ pairs2,
    int E, int npb)
{
    const int g = blockIdx.y;
    const int* e = g ? e2 : e1;
    int* bc = bcur + g * NB;
    unsigned int* pairs = g ? pairs2 : pairs1;

    __shared__ unsigned int s_ed[PART_T];         // 16 KB
    __shared__ short s_b[PART_T];                 //  8 KB (bucket per edge)
    __shared__ int s_cnt[NB], s_base[NB], s_cur[NB];
    const int tid = threadIdx.x;
    const int e0  = blockIdx.x * PART_T;
    const int ne  = min(PART_T, E - e0);

    for (int i = tid; i < NB; i += 256) { s_cnt[i] = 0; s_cur[i] = 0; }
    __syncthreads();

    for (int k = tid; k < ne; k += 256) {
        int s = e[e0 + k], d = e[E + e0 + k];
        int b = d / npb, dl = d - b * npb;
        s_ed[k] = ((unsigned)dl << 16) | (unsigned)s;
        s_b[k]  = (short)b;
        atomicAdd(&s_cnt[b], 1);
    }
    __syncthreads();
    for (int b = tid; b < NB; b += 256)
        if (s_cnt[b] > 0) s_base[b] = atomicAdd(&bc[b], s_cnt[b]);
    __syncthreads();
    for (int k = tid; k < ne; k += 256) {
        int b = s_b[k];
        int r = atomicAdd(&s_cur[b], 1);
        pairs[s_base[b] + r] = s_ed[k];
    }
}

// grid.y selects graph. One block per bucket: LDS CSR cursors (from roff),
// stream packed pairs, csr[pos]=src (writes stay in bucket's L2 window).
__global__ __launch_bounds__(256) void k_scatter3(
    const unsigned int* __restrict__ pairs1,
    const unsigned int* __restrict__ pairs2,
    const int* __restrict__ roff1, const int* __restrict__ roff2,
    int* __restrict__ csr1, int* __restrict__ csr2,
    int n, int npb)
{
    const int g = blockIdx.y;
    const unsigned int* pairs = g ? pairs2 : pairs1;
    const int* roff = g ? roff2 : roff1;
    int* csr = g ? csr2 : csr1;

    __shared__ int s_cur[MAXNPB];
    const int tid = threadIdx.x;
    const int b   = blockIdx.x;
    const int lo  = b * npb;
    if (lo >= n) return;
    const int hi = min(lo + npb, n);
    const int nd = hi - lo;

    for (int i = tid; i < nd; i += 256) s_cur[i] = roff[lo + i];
    __syncthreads();

    const int seg0 = roff[lo], seg1 = roff[hi];
    for (int p = seg0 + tid; p < seg1; p += 256) {
        unsigned int pr = pairs[p];
        int dl = (int)(pr >> 16), s = (int)(pr & 0xffffu);
        int pos = atomicAdd(&s_cur[dl], 1);
        csr[pos] = s;
    }
}

// BOTH graphs fused: 1 wave per node, lane=feature; walk csr1 then csr2 with
// 8-deep gather ILP over 128B-aligned fp16 hs rows; fused epilogue -> out.
__global__ __launch_bounds__(512) void k_agg2(
    const __half* __restrict__ hs1, const int* __restrict__ csr1,
    const int* __restrict__ roff1, const float* __restrict__ dinv1,
    const float* __restrict__ b1,
    const __half* __restrict__ hs2, const int* __restrict__ csr2,
    const int* __restrict__ roff2, const float* __restrict__ dinv2,
    const float* __restrict__ b2,
    const float* __restrict__ mw, const float* __restrict__ mlp_b,
    float* __restrict__ out, int n)
{
    int wv = threadIdx.x >> 6, lane = threadIdx.x & 63;
    int d = blockIdx.x * 8 + wv;
    if (d >= n) return;
    int fc = lane < 40 ? lane : 0;

    float v = 0.0f;
    #pragma unroll
    for (int gph = 0; gph < 2; ++gph) {
        const __half* hs  = gph ? hs2  : hs1;
        const int* csr    = gph ? csr2 : csr1;
        const int* roff   = gph ? roff2 : roff1;
        const float* dinv = gph ? dinv2 : dinv1;
        const float* bias = gph ? b2 : b1;
        int beg = roff[d], end = roff[d + 1];
        float acc = 0.0f;
        int e = beg;
        for (; e + 8 <= end; e += 8) {
            int s0 = csr[e],     s1 = csr[e + 1], s2 = csr[e + 2], s3 = csr[e + 3];
            int s4 = csr[e + 4], s5 = csr[e + 5], s6 = csr[e + 6], s7 = csr[e + 7];
            float a0 = __half2float(hs[(size_t)s0 * HSW + fc]);
            float a1 = __half2float(hs[(size_t)s1 * HSW + fc]);
            float a2 = __half2float(hs[(size_t)s2 * HSW + fc]);
            float a3 = __half2float(hs[(size_t)s3 * HSW + fc]);
            float a4 = __half2float(hs[(size_t)s4 * HSW + fc]);
            float a5 = __half2float(hs[(size_t)s5 * HSW + fc]);
            float a6 = __half2float(hs[(size_t)s6 * HSW + fc]);
            float a7 = __half2float(hs[(size_t)s7 * HSW + fc]);
            acc += ((a0 + a1) + (a2 + a3)) + ((a4 + a5) + (a6 + a7));
        }
        for (; e < end; ++e) acc += __half2float(hs[(size_t)csr[e] * HSW + fc]);

        float vg = dinv[d] * (__half2float(hs[(size_t)d * HSW + fc]) + acc) + bias[fc];
        v += fmaxf(vg, 0.0f) * mw[gph * 40 + fc];
    }
    if (lane >= 40) v = 0.0f;
    #pragma unroll
    for (int off = 32; off > 0; off >>= 1) v += __shfl_down(v, off);
    if (lane == 0) out[d] = mlp_b[0] + v;
}

extern "C" void kernel_launch(void* const* d_in, const int* in_sizes, int n_in,
                              void* d_out, int out_size, void* d_ws, size_t ws_size,
                              hipStream_t stream)
{
    const float* x      = (const float*)d_in[0];
    const int*   ei1    = (const int*)d_in[1];
    const int*   ei2    = (const int*)d_in[2];
    const float* conv_w = (const float*)d_in[3];
    const float* conv_b = (const float*)d_in[4];
    const float* lin_w  = (const float*)d_in[5];
    const float* lin_b  = (const float*)d_in[6];
    const float* w_ih   = (const float*)d_in[7];
    const float* w_hh   = (const float*)d_in[8];
    const float* b_ih   = (const float*)d_in[9];
    const float* b_hh   = (const float*)d_in[10];
    const float* g1w    = (const float*)d_in[11];
    const float* g1b    = (const float*)d_in[12];
    const float* g2w    = (const float*)d_in[13];
    const float* g2b    = (const float*)d_in[14];
    const float* mw     = (const float*)d_in[15];
    const float* mb     = (const float*)d_in[16];

    const int N = in_sizes[0] / (5 * 395);
    const int E = in_sizes[1] / 2;
    const int R = N * 5;
    float* out = (float*)d_out;

    const int npb = (N + NB - 1) / NB;
    if (npb > MAXNPB) return;     // static LDS sizing guard (N=50000 -> npb=98)
    if (N > 65536) return;        // u32 pair packing guard (src/dstLocal in 16b)

    char* wp = (char*)d_ws;
    auto alloc = [&](size_t bytes) {
        char* p = wp; wp += (bytes + 255) & ~(size_t)255; return p;
    };
    size_t seq_bytes = (size_t)4 * N * 41 * 4;
    float*  seq   = (float*)alloc(seq_bytes);
    float*  feats = (float*)alloc((size_t)N * 104 * 4);
    __half* hs1   = (__half*)alloc((size_t)N * HSW * 2);
    __half* hs2   = (__half*)alloc((size_t)N * HSW * 2);
    int*    csr1  = (int*)alloc((size_t)E * 4);
    int*    csr2  = (int*)alloc((size_t)E * 4);
    int*    cnt1  = (int*)alloc((size_t)N * 4);
    int*    cnt2  = (int*)alloc((size_t)N * 4);
    int*    roff1 = (int*)alloc((size_t)(N + 1) * 4);
    int*    roff2 = (int*)alloc((size_t)(N + 1) * 4);
    float*  dinv1 = (float*)alloc((size_t)N * 4);
    float*  dinv2 = (float*)alloc((size_t)N * 4);
    int*    bcur  = (int*)alloc((size_t)2 * NB * 4);

    // packed u32 pairs alias the (not-yet-written) seq region when they fit:
    // all pairs consumers (k_scatter3) complete on-stream before k_cnn writes seq.
    unsigned int *pairs1, *pairs2;
    if (2 * (size_t)E * 4 <= seq_bytes) {
        pairs1 = (unsigned int*)seq;
        pairs2 = pairs1 + E;
    } else {
        pairs1 = (unsigned int*)alloc((size_t)E * 4);
        pairs2 = (unsigned int*)alloc((size_t)E * 4);
    }
    if ((size_t)(wp - (char*)d_ws) > ws_size) return;  // workspace too small

    hipLaunchKernelGGL(k_zero2,    dim3((N + 255) / 256), dim3(256), 0, stream, cnt1, cnt2, N);
    hipLaunchKernelGGL(k_deg,      dim3((E + 255) / 256), dim3(256), 0, stream, ei1 + E, ei2 + E, cnt1, cnt2, E);
    hipLaunchKernelGGL(k_scan2,    dim3(2), dim3(1024), 0, stream, cnt1, roff1, dinv1, cnt2, roff2, dinv2, bcur, npb, N);
    hipLaunchKernelGGL(k_part,     dim3((E + PART_T - 1) / PART_T, 2), dim3(256), 0, stream, ei1, ei2, bcur, pairs1, pairs2, E, npb);
    hipLaunchKernelGGL(k_scatter3, dim3(NB, 2), dim3(256), 0, stream, pairs1, pairs2, roff1, roff2, csr1, csr2, N, npb);
    hipLaunchKernelGGL(k_cnn,      dim3((R + 63) / 64), dim3(512), 0, stream, x, conv_w, conv_b, lin_w, lin_b, seq, feats, R, N);
    hipLaunchKernelGGL(k_gru,      dim3((N + 127) / 128), dim3(512), 0, stream, seq, w_ih, w_hh, b_ih, b_hh, feats, N);
    hipLaunchKernelGGL(k_hw,       dim3((N + 127) / 128), dim3(256), 0, stream, feats, g1w, g2w, dinv1, dinv2, hs1, hs2, N);
    hipLaunchKernelGGL(k_agg2,     dim3((N + 7) / 8), dim3(512), 0, stream,
                       hs1, csr1, roff1, dinv1, g1b,
                       hs2, csr2, roff2, dinv2, g2b,
                       mw, mb, out, N);
}

// Round 18
// 717.725 us; speedup vs baseline: 1.0172x; 1.0172x over previous
//
#include <hip/hip_runtime.h>
#include <hip/hip_fp16.h>
#include <math.h>

// ---------------------------------------------------------------------------
// Pipeline:
//  k_zero2     : zero degree counters
//  k_deg       : in-degree count per dst (both graphs), int atomics
//  k_scan2     : 2 blocks (one per graph): exclusive scan -> roff, dinv,
//                + fused per-bucket cursor init (bcur = roff[bucket_lo])
//  k_part      : grid.y=graph; stage 4096 edges in LDS, histogram over 512
//                dst-buckets, reserve ranges, write u32 (dstLocal<<16|src)
//  k_scatter3  : grid.y=graph; one block per bucket, LDS CSR cursors,
//                stream packed pairs -> csr[pos]=src (L2-window writes)
//  k_cnn       : conv1d(16,k40,s88)+relu + linear 80->40+relu -> seq/feats
//  k_gru       : tiled f32 GRU (best measured): 128 nodes/block, 512 thr
//  k_hw        : hs_g[n][0..39] = fp16(dinv*(feats@Wg)), row stride 64
//  k_agg2      : BOTH graphs INTERLEAVED per node-wave: 8+8-deep gather ILP
//                (16 loads in flight -> half the latency rounds of the
//                sequential-graphs version), fused bias+relu+MLP -> out
// ---------------------------------------------------------------------------

#define NB      512   // dst buckets
#define MAXNPB  104   // max dst nodes per bucket (N=50000 -> npb=98)
#define PART_T  4096  // edges staged per k_part block
#define HSW     64    // hs row stride in halves (128B-aligned rows)

__global__ __launch_bounds__(512) void k_cnn(
    const float* __restrict__ x,       // [R][395]
    const float* __restrict__ conv_w,  // [16][40]
    const float* __restrict__ conv_b,  // [16]
    const float* __restrict__ lin_w,   // [40][80]
    const float* __restrict__ lin_b,   // [40]
    float* __restrict__ seq,           // [4][N][41]
    float* __restrict__ feats,         // [N][104]
    int nrows, int nnodes)
{
    __shared__ __align__(16) float smem[64 * 200];   // 51.2 KB (sig, then c)
    __shared__ __align__(16) float s_cw[16][44];
    __shared__ __align__(16) float s_lw[40][84];
    __shared__ float s_cb[16];
    __shared__ float s_lb[40];

    const int tid = threadIdx.x;
    const int r0  = blockIdx.x * 64;

    float sg[25];
    #pragma unroll
    for (int it = 0; it < 25; ++it) {
        int i = tid + it * 512;
        int row = i / 200, e = i - row * 200;
        int p = e / 40, kk = e - p * 40;
        int gr = r0 + row; if (gr >= nrows) gr = nrows - 1;
        sg[it] = x[(size_t)gr * 395 + 3 + 88 * p + kk];
    }

    for (int i = tid; i < 640;  i += 512) s_cw[i / 40][i % 40] = conv_w[i];
    for (int i = tid; i < 3200; i += 512) s_lw[i / 80][i % 80] = lin_w[i];
    if (tid < 16) s_cb[tid] = conv_b[tid];
    if (tid >= 64 && tid < 104) s_lb[tid - 64] = lin_b[tid - 64];

    if (tid < 64) {
        int gr = r0 + tid;
        if (gr < nrows) {
            float y = x[(size_t)gr * 395 + 2];
            int node = gr / 5, t = gr - node * 5;
            if (t < 4) seq[(t * nnodes + node) * 41 + 40] = y;
        }
    }

    #pragma unroll
    for (int it = 0; it < 25; ++it) {
        int i = tid + it * 512;
        int row = i / 200, e = i - row * 200;
        smem[row * 200 + e] = sg[it];
    }
    __syncthreads();

    const int row = tid >> 3, cg = tid & 7;
    float creg[2][5];
    {
        float acc[2][5];
        #pragma unroll
        for (int cc = 0; cc < 2; ++cc) {
            float b = s_cb[2 * cg + cc];
            #pragma unroll
            for (int p = 0; p < 5; ++p) acc[cc][p] = b;
        }
        #pragma unroll
        for (int k4 = 0; k4 < 40; k4 += 4) {
            float4 sv[5];
            #pragma unroll
            for (int p = 0; p < 5; ++p)
                sv[p] = *(const float4*)&smem[row * 200 + p * 40 + k4];
            #pragma unroll
            for (int cc = 0; cc < 2; ++cc) {
                float4 w4 = *(const float4*)&s_cw[2 * cg + cc][k4];
                #pragma unroll
                for (int p = 0; p < 5; ++p)
                    acc[cc][p] += w4.x * sv[p].x + w4.y * sv[p].y + w4.z * sv[p].z + w4.w * sv[p].w;
            }
        }
        #pragma unroll
        for (int cc = 0; cc < 2; ++cc)
            #pragma unroll
            for (int p = 0; p < 5; ++p) creg[cc][p] = fmaxf(acc[cc][p], 0.0f);
    }
    __syncthreads();

    #pragma unroll
    for (int cc = 0; cc < 2; ++cc)
        #pragma unroll
        for (int p = 0; p < 5; ++p)
            smem[row * 84 + (2 * cg + cc) * 5 + p] = creg[cc][p];
    __syncthreads();

    {
        const int jg = tid & 7;
        float acc[5];
        #pragma unroll
        for (int jj = 0; jj < 5; ++jj) acc[jj] = s_lb[5 * jg + jj];
        #pragma unroll
        for (int i4 = 0; i4 < 80; i4 += 4) {
            float4 c0 = *(const float4*)&smem[row * 84 + i4];
            #pragma unroll
            for (int jj = 0; jj < 5; ++jj) {
                float4 w4 = *(const float4*)&s_lw[5 * jg + jj][i4];
                acc[jj] += w4.x * c0.x + w4.y * c0.y + w4.z * c0.z + w4.w * c0.w;
            }
        }
        int gr = r0 + row;
        if (gr < nrows) {
            int node = gr / 5, t = gr - node * 5;
            #pragma unroll
            for (int jj = 0; jj < 5; ++jj) {
                float v = fmaxf(acc[jj], 0.0f);
                if (t < 4) seq[(t * nnodes + node) * 41 + 5 * jg + jj] = v;
                else       feats[node * 104 + 5 * jg + jj] = v;
            }
        }
    }
}

// tiled f32 GRU (best measured): 128 nodes/block, 512 threads,
// weights+h+x in LDS, next-step x prefetched into registers.
__global__ __launch_bounds__(512) void k_gru(
    const float* __restrict__ seq,    // [4][N][41]
    const float* __restrict__ w_ih,   // [192][41]
    const float* __restrict__ w_hh,   // [192][64]
    const float* __restrict__ b_ih,
    const float* __restrict__ b_hh,
    float* __restrict__ feats,        // [N][104]
    int nnodes)
{
    __shared__ __align__(16) float s_wi[41][192];
    __shared__ __align__(16) float s_wh[64][192];
    __shared__ __align__(16) float s_h[64][132];
    __shared__ __align__(16) float s_x[41][132];
    __shared__ float s_bi[192], s_bh[192];

    const int tid  = threadIdx.x;
    const int nblk = blockIdx.x * 128;

    float xr[11];
    #pragma unroll
    for (int r = 0; r < 11; ++r) {
        int i = tid + r * 512;
        if (i < 5248) {
            int nl = i / 41, k = i - nl * 41;
            int node = nblk + nl; if (node >= nnodes) node = nnodes - 1;
            xr[r] = seq[(size_t)node * 41 + k];
        }
    }

    for (int i = tid; i < 192 * 41; i += 512) { int g = i / 41, k = i - g * 41; s_wi[k][g] = w_ih[i]; }
    for (int i = tid; i < 192 * 64; i += 512) { int g = i >> 6,  k = i & 63;    s_wh[k][g] = w_hh[i]; }
    if (tid < 192) { s_bi[tid] = b_ih[tid]; s_bh[tid] = b_hh[tid]; }
    for (int i = tid; i < 64 * 132; i += 512) ((float*)s_h)[i] = 0.0f;

    #pragma unroll
    for (int r = 0; r < 11; ++r) {
        int i = tid + r * 512;
        if (i < 5248) { int nl = i / 41, k = i - nl * 41; s_x[k][nl] = xr[r]; }
    }
    __syncthreads();

    const int jg = tid & 31, ngp = tid >> 5;
    const int j0 = 2 * jg, n0 = 8 * ngp;

    float hreg[2][8];
    #pragma unroll
    for (int a = 0; a < 2; ++a)
        #pragma unroll
        for (int b = 0; b < 8; ++b) hreg[a][b] = 0.0f;

    for (int t = 0; t < 4; ++t) {
        if (t < 3) {
            #pragma unroll
            for (int r = 0; r < 11; ++r) {
                int i = tid + r * 512;
                if (i < 5248) {
                    int nl = i / 41, k = i - nl * 41;
                    int node = nblk + nl; if (node >= nnodes) node = nnodes - 1;
                    xr[r] = seq[(size_t)((t + 1) * nnodes + node) * 41 + k];
                }
            }
        }

        float ar[2][8], az[2][8], ani[2][8], anh[2][8];
        #pragma unroll
        for (int a = 0; a < 2; ++a)
            #pragma unroll
            for (int b = 0; b < 8; ++b) { ar[a][b]=0.f; az[a][b]=0.f; ani[a][b]=0.f; anh[a][b]=0.f; }

        for (int k = 0; k < 41; ++k) {
            float4 xa = *(const float4*)&s_x[k][n0];
            float4 xb = *(const float4*)&s_x[k][n0 + 4];
            float xv[8] = {xa.x,xa.y,xa.z,xa.w,xb.x,xb.y,xb.z,xb.w};
            float2 wr = *(const float2*)&s_wi[k][j0];
            float2 wz = *(const float2*)&s_wi[k][64 + j0];
            float2 wn = *(const float2*)&s_wi[k][128 + j0];
            #pragma unroll
            for (int nn = 0; nn < 8; ++nn) {
                ar[0][nn] += wr.x*xv[nn]; ar[1][nn] += wr.y*xv[nn];
                az[0][nn] += wz.x*xv[nn]; az[1][nn] += wz.y*xv[nn];
                ani[0][nn]+= wn.x*xv[nn]; ani[1][nn]+= wn.y*xv[nn];
            }
        }
        for (int k = 0; k < 64; ++k) {
            float4 ha = *(const float4*)&s_h[k][n0];
            float4 hb = *(const float4*)&s_h[k][n0 + 4];
            float hv[8] = {ha.x,ha.y,ha.z,ha.w,hb.x,hb.y,hb.z,hb.w};
            float2 wr = *(const float2*)&s_wh[k][j0];
            float2 wz = *(const float2*)&s_wh[k][64 + j0];
            float2 wn = *(const float2*)&s_wh[k][128 + j0];
            #pragma unroll
            for (int nn = 0; nn < 8; ++nn) {
                ar[0][nn] += wr.x*hv[nn]; ar[1][nn] += wr.y*hv[nn];
                az[0][nn] += wz.x*hv[nn]; az[1][nn] += wz.y*hv[nn];
                anh[0][nn]+= wn.x*hv[nn]; anh[1][nn]+= wn.y*hv[nn];
            }
        }

        #pragma unroll
        for (int jj = 0; jj < 2; ++jj) {
            int j = j0 + jj;
            float br  = s_bi[j]      + s_bh[j];
            float bz  = s_bi[64 + j] + s_bh[64 + j];
            float bin = s_bi[128 + j], bhn = s_bh[128 + j];
            #pragma unroll
            for (int nn = 0; nn < 8; ++nn) {
                float r = 1.0f / (1.0f + expf(-(ar[jj][nn] + br)));
                float z = 1.0f / (1.0f + expf(-(az[jj][nn] + bz)));
                float g = tanhf(ani[jj][nn] + bin + r * (anh[jj][nn] + bhn));
                hreg[jj][nn] = (1.0f - z) * g + z * hreg[jj][nn];
            }
        }
        __syncthreads();

        if (t < 3) {
            #pragma unroll
            for (int jj = 0; jj < 2; ++jj) {
                *(float4*)&s_h[j0+jj][n0]     = make_float4(hreg[jj][0],hreg[jj][1],hreg[jj][2],hreg[jj][3]);
                *(float4*)&s_h[j0+jj][n0 + 4] = make_float4(hreg[jj][4],hreg[jj][5],hreg[jj][6],hreg[jj][7]);
            }
            #pragma unroll
            for (int r = 0; r < 11; ++r) {
                int i = tid + r * 512;
                if (i < 5248) { int nl = i / 41, k = i - nl * 41; s_x[k][nl] = xr[r]; }
            }
            __syncthreads();
        }
    }

    #pragma unroll
    for (int jj = 0; jj < 2; ++jj)
        #pragma unroll
        for (int nn = 0; nn < 8; ++nn) {
            int node = nblk + n0 + nn;
            if (node < nnodes) feats[node * 104 + 40 + j0 + jj] = hreg[jj][nn];
        }
}

__global__ __launch_bounds__(256) void k_hw(
    const float* __restrict__ feats,   // [N][104]
    const float* __restrict__ w1,      // [104][40]
    const float* __restrict__ w2,      // [104][40]
    const float* __restrict__ dinv1,
    const float* __restrict__ dinv2,
    __half* __restrict__ hs1,          // [N][HSW] fp16, 40 used
    __half* __restrict__ hs2,
    int nnodes)
{
    __shared__ __align__(16) float s_f[128][108];
    __shared__ __align__(16) float s_w[80][108];
    __shared__ float s_d[2][128];

    const int tid  = threadIdx.x;
    const int nblk = blockIdx.x * 128;

    for (int i = tid; i < 128 * 104; i += 256) {
        int n = i / 104, k = i - n * 104;
        int node = nblk + n; if (node >= nnodes) node = nnodes - 1;
        s_f[n][k] = feats[node * 104 + k];
    }
    for (int i = tid; i < 80 * 104; i += 256) {
        int o = i / 104, k = i - o * 104;
        s_w[o][k] = (o < 40) ? w1[k * 40 + o] : w2[k * 40 + (o - 40)];
    }
    if (tid < 128) {
        int node = nblk + tid; if (node >= nnodes) node = nnodes - 1;
        s_d[0][tid] = dinv1[node]; s_d[1][tid] = dinv2[node];
    }
    __syncthreads();

    const int og = tid & 7, ngp = tid >> 3;
    const int o0 = 10 * og, n0 = 4 * ngp;
    float acc[4][10];
    #pragma unroll
    for (int a = 0; a < 4; ++a)
        #pragma unroll
        for (int b = 0; b < 10; ++b) acc[a][b] = 0.0f;

    for (int k4 = 0; k4 < 104; k4 += 4) {
        float4 f[4];
        #pragma unroll
        for (int nn = 0; nn < 4; ++nn) f[nn] = *(const float4*)&s_f[n0 + nn][k4];
        #pragma unroll
        for (int oo = 0; oo < 10; ++oo) {
            float4 w4 = *(const float4*)&s_w[o0 + oo][k4];
            #pragma unroll
            for (int nn = 0; nn < 4; ++nn)
                acc[nn][oo] += w4.x * f[nn].x + w4.y * f[nn].y + w4.z * f[nn].z + w4.w * f[nn].w;
        }
    }
    #pragma unroll
    for (int nn = 0; nn < 4; ++nn) {
        int node = nblk + n0 + nn;
        if (node >= nnodes) continue;
        #pragma unroll
        for (int oo = 0; oo < 10; oo += 2) {
            int o = o0 + oo;
            float dscale = (o < 40) ? s_d[0][n0 + nn] : s_d[1][n0 + nn];
            __half2 h2 = __floats2half2_rn(dscale * acc[nn][oo], dscale * acc[nn][oo + 1]);
            if (o < 40) *(__half2*)&hs1[node * HSW + o]        = h2;
            else        *(__half2*)&hs2[node * HSW + (o - 40)] = h2;
        }
    }
}

__global__ void k_zero2(int* a, int* b, int n) {
    int i = blockIdx.x * 256 + threadIdx.x;
    if (i < n) { a[i] = 0; b[i] = 0; }
}

__global__ void k_deg(const int* __restrict__ d1, const int* __restrict__ d2,
                      int* c1, int* c2, int E) {
    int i = blockIdx.x * 256 + threadIdx.x;
    if (i < E) { atomicAdd(&c1[d1[i]], 1); atomicAdd(&c2[d2[i]], 1); }
}

// 2 blocks: blockIdx.x==0 -> graph1, ==1 -> graph2. Scan + dinv + fused bcur.
__global__ __launch_bounds__(1024) void k_scan2(
    const int* __restrict__ cnt1, int* __restrict__ roff1, float* __restrict__ dinv1,
    const int* __restrict__ cnt2, int* __restrict__ roff2, float* __restrict__ dinv2,
    int* __restrict__ bcur, int npb, int n)
{
    const int* cnt  = blockIdx.x ? cnt2  : cnt1;
    int*       roff = blockIdx.x ? roff2 : roff1;
    float*     dinv = blockIdx.x ? dinv2 : dinv1;
    int*       bc   = bcur + (blockIdx.x ? NB : 0);

    __shared__ int sp[1024];
    int t = threadIdx.x;
    int C = (n + 1023) >> 10;
    int i0 = t * C, i1 = min(i0 + C, n);
    int s = 0;
    for (int i = i0; i < i1; ++i) s += cnt[i];
    sp[t] = s;
    __syncthreads();
    for (int off = 1; off < 1024; off <<= 1) {
        int v = (t >= off) ? sp[t - off] : 0;
        __syncthreads();
        sp[t] += v;
        __syncthreads();
    }
    int run = sp[t] - s;
    for (int i = i0; i < i1; ++i) {
        int c = cnt[i];
        roff[i] = run;
        dinv[i] = rsqrtf((float)(c + 1));
        run += c;
    }
    if (t == 1023) roff[n] = sp[1023];
    __syncthreads();
    if (t < NB) {
        int lo = min(t * npb, n);
        bc[t] = roff[lo];
    }
}

// grid.y selects graph. Stage PART_T edges in LDS, histogram over NB buckets,
// reserve exact global ranges, write u32 (dstLocal<<16 | src) by bucket.
__global__ __launch_bounds__(256) void k_part(
    const int* __restrict__ e1, const int* __restrict__ e2,
    int* __restrict__ bcur,             // [2*NB]
    unsigned int* __restrict__ pairs1,
    unsigned int* __restrict__ pairs2,
    int E, int npb)
{
    const int g = blockIdx.y;
    const int* e = g ? e2 : e1;
    int* bc = bcur + g * NB;
    unsigned int* pairs = g ? pairs2 : pairs1;

    __shared__ unsigned int s_ed[PART_T];         // 16 KB
    __shared__ short s_b[PART_T];                 //  8 KB (bucket per edge)
    __shared__ int s_cnt[NB], s_base[NB], s_cur[NB];
    const int tid = threadIdx.x;
    const int e0  = blockIdx.x * PART_T;
    const int ne  = min(PART_T, E - e0);

    for (int i = tid; i < NB; i += 256) { s_cnt[i] = 0; s_cur[i] = 0; }
    __syncthreads();

    for (int k = tid; k < ne; k += 256) {
        int s = e[e0 + k], d = e[E + e0 + k];
        int b = d / npb, dl = d - b * npb;
        s_ed[k] = ((unsigned)dl << 16) | (unsigned)s;
        s_b[k]  = (short)b;
        atomicAdd(&s_cnt[b], 1);
    }
    __syncthreads();
    for (int b = tid; b < NB; b += 256)
        if (s_cnt[b] > 0) s_base[b] = atomicAdd(&bc[b], s_cnt[b]);
    __syncthreads();
    for (int k = tid; k < ne; k += 256) {
        int b = s_b[k];
        int r = atomicAdd(&s_cur[b], 1);
        pairs[s_base[b] + r] = s_ed[k];
    }
}

// grid.y selects graph. One block per bucket: LDS CSR cursors (from roff),
// stream packed pairs, csr[pos]=src (writes stay in bucket's L2 window).
__global__ __launch_bounds__(256) void k_scatter3(
    const unsigned int* __restrict__ pairs1,
    const unsigned int* __restrict__ pairs2,
    const int* __restrict__ roff1, const int* __restrict__ roff2,
    int* __restrict__ csr1, int* __restrict__ csr2,
    int n, int npb)
{
    const int g = blockIdx.y;
    const unsigned int* pairs = g ? pairs2 : pairs1;
    const int* roff = g ? roff2 : roff1;
    int* csr = g ? csr2 : csr1;

    __shared__ int s_cur[MAXNPB];
    const int tid = threadIdx.x;
    const int b   = blockIdx.x;
    const int lo  = b * npb;
    if (lo >= n) return;
    const int hi = min(lo + npb, n);
    const int nd = hi - lo;

    for (int i = tid; i < nd; i += 256) s_cur[i] = roff[lo + i];
    __syncthreads();

    const int seg0 = roff[lo], seg1 = roff[hi];
    for (int p = seg0 + tid; p < seg1; p += 256) {
        unsigned int pr = pairs[p];
        int dl = (int)(pr >> 16), s = (int)(pr & 0xffffu);
        int pos = atomicAdd(&s_cur[dl], 1);
        csr[pos] = s;
    }
}

// BOTH graphs INTERLEAVED: 1 wave/node, lane=feature. Main loop walks csr1
// and csr2 8-deep EACH (16 independent gathers in flight), then per-graph
// tails; fused bias+relu+MLP partial dot -> out.
__global__ __launch_bounds__(512) void k_agg2(
    const __half* __restrict__ hs1, const int* __restrict__ csr1,
    const int* __restrict__ roff1, const float* __restrict__ dinv1,
    const float* __restrict__ b1,
    const __half* __restrict__ hs2, const int* __restrict__ csr2,
    const int* __restrict__ roff2, const float* __restrict__ dinv2,
    const float* __restrict__ b2,
    const float* __restrict__ mw, const float* __restrict__ mlp_b,
    float* __restrict__ out, int n)
{
    int wv = threadIdx.x >> 6, lane = threadIdx.x & 63;
    int d = blockIdx.x * 8 + wv;
    if (d >= n) return;
    int fc = lane < 40 ? lane : 0;

    int e1 = roff1[d], end1 = roff1[d + 1];
    int e2 = roff2[d], end2 = roff2[d + 1];
    float acc1 = 0.0f, acc2 = 0.0f;

    // interleaved main loop: 8 gathers per graph in flight (16 total)
    for (; e1 + 8 <= end1 && e2 + 8 <= end2; e1 += 8, e2 += 8) {
        int a0 = csr1[e1],     a1 = csr1[e1 + 1], a2 = csr1[e1 + 2], a3 = csr1[e1 + 3];
        int a4 = csr1[e1 + 4], a5 = csr1[e1 + 5], a6 = csr1[e1 + 6], a7 = csr1[e1 + 7];
        int c0 = csr2[e2],     c1 = csr2[e2 + 1], c2 = csr2[e2 + 2], c3 = csr2[e2 + 3];
        int c4 = csr2[e2 + 4], c5 = csr2[e2 + 5], c6 = csr2[e2 + 6], c7 = csr2[e2 + 7];
        float f0 = __half2float(hs1[(size_t)a0 * HSW + fc]);
        float f1 = __half2float(hs1[(size_t)a1 * HSW + fc]);
        float f2 = __half2float(hs1[(size_t)a2 * HSW + fc]);
        float f3 = __half2float(hs1[(size_t)a3 * HSW + fc]);
        float f4 = __half2float(hs1[(size_t)a4 * HSW + fc]);
        float f5 = __half2float(hs1[(size_t)a5 * HSW + fc]);
        float f6 = __half2float(hs1[(size_t)a6 * HSW + fc]);
        float f7 = __half2float(hs1[(size_t)a7 * HSW + fc]);
        float g0 = __half2float(hs2[(size_t)c0 * HSW + fc]);
        float g1 = __half2float(hs2[(size_t)c1 * HSW + fc]);
        float g2 = __half2float(hs2[(size_t)c2 * HSW + fc]);
        float g3 = __half2float(hs2[(size_t)c3 * HSW + fc]);
        float g4 = __half2float(hs2[(size_t)c4 * HSW + fc]);
        float g5 = __half2float(hs2[(size_t)c5 * HSW + fc]);
        float g6 = __half2float(hs2[(size_t)c6 * HSW + fc]);
        float g7 = __half2float(hs2[(size_t)c7 * HSW + fc]);
        acc1 += ((f0 + f1) + (f2 + f3)) + ((f4 + f5) + (f6 + f7));
        acc2 += ((g0 + g1) + (g2 + g3)) + ((g4 + g5) + (g6 + g7));
    }
    // graph-1 tail (8-deep then scalar)
    for (; e1 + 8 <= end1; e1 += 8) {
        int a0 = csr1[e1],     a1 = csr1[e1 + 1], a2 = csr1[e1 + 2], a3 = csr1[e1 + 3];
        int a4 = csr1[e1 + 4], a5 = csr1[e1 + 5], a6 = csr1[e1 + 6], a7 = csr1[e1 + 7];
        float f0 = __half2float(hs1[(size_t)a0 * HSW + fc]);
        float f1 = __half2float(hs1[(size_t)a1 * HSW + fc]);
        float f2 = __half2float(hs1[(size_t)a2 * HSW + fc]);
        float f3 = __half2float(hs1[(size_t)a3 * HSW + fc]);
        float f4 = __half2float(hs1[(size_t)a4 * HSW + fc]);
        float f5 = __half2float(hs1[(size_t)a5 * HSW + fc]);
        float f6 = __half2float(hs1[(size_t)a6 * HSW + fc]);
        float f7 = __half2float(hs1[(size_t)a7 * HSW + fc]);
        acc1 += ((f0 + f1) + (f2 + f3)) + ((f4 + f5) + (f6 + f7));
    }
    for (; e1 < end1; ++e1) acc1 += __half2float(hs1[(size_t)csr1[e1] * HSW + fc]);
    // graph-2 tail
    for (; e2 + 8 <= end2; e2 += 8) {
        int c0 = csr2[e2],     c1 = csr2[e2 + 1], c2 = csr2[e2 + 2], c3 = csr2[e2 + 3];
        int c4 = csr2[e2 + 4], c5 = csr2[e2 + 5], c6 = csr2[e2 + 6], c7 = csr2[e2 + 7];
        float g0 = __half2float(hs2[(size_t)c0 * HSW + fc]);
        float g1 = __half2float(hs2[(size_t)c1 * HSW + fc]);
        float g2 = __half2float(hs2[(size_t)c2 * HSW + fc]);
        float g3 = __half2float(hs2[(size_t)c3 * HSW + fc]);
        float g4 = __half2float(hs2[(size_t)c4 * HSW + fc]);
        float g5 = __half2float(hs2[(size_t)c5 * HSW + fc]);
        float g6 = __half2float(hs2[(size_t)c6 * HSW + fc]);
        float g7 = __half2float(hs2[(size_t)c7 * HSW + fc]);
        acc2 += ((g0 + g1) + (g2 + g3)) + ((g4 + g5) + (g6 + g7));
    }
    for (; e2 < end2; ++e2) acc2 += __half2float(hs2[(size_t)csr2[e2] * HSW + fc]);

    float v1 = dinv1[d] * (__half2float(hs1[(size_t)d * HSW + fc]) + acc1) + b1[fc];
    float v2 = dinv2[d] * (__half2float(hs2[(size_t)d * HSW + fc]) + acc2) + b2[fc];
    float v  = fmaxf(v1, 0.0f) * mw[fc] + fmaxf(v2, 0.0f) * mw[40 + fc];
    if (lane >= 40) v = 0.0f;
    #pragma unroll
    for (int off = 32; off > 0; off >>= 1) v += __shfl_down(v, off);
    if (lane == 0) out[d] = mlp_b[0] + v;
}

extern "C" void kernel_launch(void* const* d_in, const int* in_sizes, int n_in,
                              void* d_out, int out_size, void* d_ws, size_t ws_size,
                              hipStream_t stream)
{
    const float* x      = (const float*)d_in[0];
    const int*   ei1    = (const int*)d_in[1];
    const int*   ei2    = (const int*)d_in[2];
    const float* conv_w = (const float*)d_in[3];
    const float* conv_b = (const float*)d_in[4];
    const float* lin_w  = (const float*)d_in[5];
    const float* lin_b  = (const float*)d_in[6];
    const float* w_ih   = (const float*)d_in[7];
    const float* w_hh   = (const float*)d_in[8];
    const float* b_ih   = (const float*)d_in[9];
    const float* b_hh   = (const float*)d_in[10];
    const float* g1w    = (const float*)d_in[11];
    const float* g1b    = (const float*)d_in[12];
    const float* g2w    = (const float*)d_in[13];
    const float* g2b    = (const float*)d_in[14];
    const float* mw     = (const float*)d_in[15];
    const float* mb     = (const float*)d_in[16];

    const int N = in_sizes[0] / (5 * 395);
    const int E = in_sizes[1] / 2;
    const int R = N * 5;
    float* out = (float*)d_out;

    const int npb = (N + NB - 1) / NB;
    if (npb > MAXNPB) return;     // static LDS sizing guard (N=50000 -> npb=98)
    if (N > 65536) return;        // u32 pair packing guard

    char* wp = (char*)d_ws;
    auto alloc = [&](size_t bytes) {
        char* p = wp; wp += (bytes + 255) & ~(size_t)255; return p;
    };
    size_t seq_bytes = (size_t)4 * N * 41 * 4;
    float*  seq   = (float*)alloc(seq_bytes);
    float*  feats = (float*)alloc((size_t)N * 104 * 4);
    __half* hs1   = (__half*)alloc((size_t)N * HSW * 2);
    __half* hs2   = (__half*)alloc((size_t)N * HSW * 2);
    int*    csr1  = (int*)alloc((size_t)E * 4);
    int*    csr2  = (int*)alloc((size_t)E * 4);
    int*    cnt1  = (int*)alloc((size_t)N * 4);
    int*    cnt2  = (int*)alloc((size_t)N * 4);
    int*    roff1 = (int*)alloc((size_t)(N + 1) * 4);
    int*    roff2 = (int*)alloc((size_t)(N + 1) * 4);
    float*  dinv1 = (float*)alloc((size_t)N * 4);
    float*  dinv2 = (float*)alloc((size_t)N * 4);
    int*    bcur  = (int*)alloc((size_t)2 * NB * 4);

    unsigned int *pairs1, *pairs2;
    if (2 * (size_t)E * 4 <= seq_bytes) {
        pairs1 = (unsigned int*)seq;
        pairs2 = pairs1 + E;
    } else {
        pairs1 = (unsigned int*)alloc((size_t)E * 4);
        pairs2 = (unsigned int*)alloc((size_t)E * 4);
    }
    if ((size_t)(wp - (char*)d_ws) > ws_size) return;  // workspace too small

    hipLaunchKernelGGL(k_zero2,    dim3((N + 255) / 256), dim3(256), 0, stream, cnt1, cnt2, N);
    hipLaunchKernelGGL(k_deg,      dim3((E + 255) / 256), dim3(256), 0, stream, ei1 + E, ei2 + E, cnt1, cnt2, E);
    hipLaunchKernelGGL(k_scan2,    dim3(2), dim3(1024), 0, stream, cnt1, roff1, dinv1, cnt2, roff2, dinv2, bcur, npb, N);
    hipLaunchKernelGGL(k_part,     dim3((E + PART_T - 1) / PART_T, 2), dim3(256), 0, stream, ei1, ei2, bcur, pairs1, pairs2, E, npb);
    hipLaunchKernelGGL(k_scatter3, dim3(NB, 2), dim3(256), 0, stream, pairs1, pairs2, roff1, roff2, csr1, csr2, N, npb);
    hipLaunchKernelGGL(k_cnn,      dim3((R + 63) / 64), dim3(512), 0, stream, x, conv_w, conv_b, lin_w, lin_b, seq, feats, R, N);
    hipLaunchKernelGGL(k_gru,      dim3((N + 127) / 128), dim3(512), 0, stream, seq, w_ih, w_hh, b_ih, b_hh, feats, N);
    hipLaunchKernelGGL(k_hw,       dim3((N + 127) / 128), dim3(256), 0, stream, feats, g1w, g2w, dinv1, dinv2, hs1, hs2, N);
    hipLaunchKernelGGL(k_agg2,     dim3((N + 7) / 8), dim3(512), 0, stream,
                       hs1, csr1, roff1, dinv1, g1b,
                       hs2, csr2, roff2, dinv2, g2b,
                       mw, mb, out, N);
}